// Round 3
// baseline (1531.297 us; speedup 1.0000x reference)
//
#include <hip/hip_runtime.h>

typedef __attribute__((ext_vector_type(8))) short short8;
typedef __attribute__((ext_vector_type(4))) float f32x4;
typedef unsigned short u16;
typedef unsigned int u32;

#define NB   16
#define NLQ  2048
#define NLK  2048
#define NH   1024

// ---------------- helpers ----------------
__device__ __forceinline__ u16 f2bf(float x){
  u32 u = __float_as_uint(x);
  return (u16)((u + 0x7fffu + ((u >> 16) & 1u)) >> 16);
}
__device__ __forceinline__ float bf2f(u16 h){ return __uint_as_float(((u32)h) << 16); }

__device__ __forceinline__ void split_bf(float x, u16& hi, u16& lo){
  u16 h = f2bf(x);
  float r = x - bf2f(h);
  hi = h; lo = f2bf(r);
}

typedef const __attribute__((address_space(1))) void* gas_ptr;
typedef __attribute__((address_space(3))) void* las_ptr;

__device__ __forceinline__ void gll16(const void* g, void* l){
  __builtin_amdgcn_global_load_lds((gas_ptr)g, (las_ptr)l, 16, 0, 0);
}

// inline-asm ds_read_b128: compiler-invisible LDS read (manual waitcnt discipline)
template<int IMM>
__device__ __forceinline__ short8 dsr(u32 base){
  short8 r;
  asm volatile("ds_read_b128 %0, %1 offset:%2" : "=v"(r) : "v"(base), "n"(IMM));
  return r;
}

#define MFMA16(a,b,c) __builtin_amdgcn_mfma_f32_16x16x32_bf16((a),(b),(c),0,0,0)

__device__ __forceinline__ float wredmax(float v){
#pragma unroll
  for (int off = 32; off > 0; off >>= 1) v = fmaxf(v, __shfl_xor(v, off, 64));
  return v;
}
__device__ __forceinline__ float wredsum(float v){
#pragma unroll
  for (int off = 32; off > 0; off >>= 1) v += __shfl_xor(v, off, 64);
  return v;
}

// ---------------- converts ----------------
__global__ void conv_q(const float* __restrict__ Q, u16* __restrict__ CB, u16* __restrict__ Qlo){
  size_t i = (size_t)blockIdx.x*256 + threadIdx.x;
  float4 v = ((const float4*)Q)[i];
  size_t e = i*4;
  size_t row = e >> 10;
  int h = (int)(e & 1023);
  u16 h0,h1,h2,h3,l0,l1,l2,l3;
  split_bf(v.x,h0,l0); split_bf(v.y,h1,l1); split_bf(v.z,h2,l2); split_bf(v.w,h3,l3);
  ushort4 hv; hv.x=h0; hv.y=h1; hv.z=h2; hv.w=h3;
  ushort4 lv; lv.x=l0; lv.y=l1; lv.z=l2; lv.w=l3;
  *(ushort4*)(CB + row*2048 + 1024 + h) = hv;
  *(ushort4*)(Qlo + row*1024 + h) = lv;
}

__global__ void conv_c(const float* __restrict__ C, u16* __restrict__ Chi,
                       u16* __restrict__ Clo, u16* __restrict__ CT){
  __shared__ u16 tile[64][65];
  const int b = blockIdx.z;
  const int k0 = blockIdx.y*64, h0 = blockIdx.x*64;
  const float* Cb = C + ((size_t)b*NLK + k0)*NH + h0;
  const int t = threadIdx.x;
#pragma unroll
  for (int i = 0; i < 4; ++i){
    int q = i*256 + t;
    int r = q >> 4;
    int c4 = (q & 15) * 4;
    float4 v = *(const float4*)(Cb + (size_t)r*NH + c4);
    u16 h0_,h1_,h2_,h3_,l0_,l1_,l2_,l3_;
    split_bf(v.x,h0_,l0_); split_bf(v.y,h1_,l1_); split_bf(v.z,h2_,l2_); split_bf(v.w,h3_,l3_);
    size_t base = ((size_t)b*NLK + k0 + r)*NH + h0 + c4;
    ushort4 hv; hv.x=h0_; hv.y=h1_; hv.z=h2_; hv.w=h3_;
    ushort4 lv; lv.x=l0_; lv.y=l1_; lv.z=l2_; lv.w=l3_;
    *(ushort4*)(Chi + base) = hv;
    *(ushort4*)(Clo + base) = lv;
    tile[r][c4+0]=h0_; tile[r][c4+1]=h1_; tile[r][c4+2]=h2_; tile[r][c4+3]=h3_;
  }
  __syncthreads();
#pragma unroll
  for (int i = 0; i < 4; ++i){
    int q = i*256 + t;
    int hl = q >> 4;
    int k4 = (q & 15) * 4;
    ushort4 o;
    o.x = tile[k4+0][hl]; o.y = tile[k4+1][hl]; o.z = tile[k4+2][hl]; o.w = tile[k4+3][hl];
    *(ushort4*)(CT + ((size_t)b*NH + h0 + hl)*NLK + k0 + k4) = o;
  }
}

__global__ void conv_w(const float* __restrict__ W, u16* __restrict__ Wbf){
  size_t i = (size_t)blockIdx.x*256 + threadIdx.x;
  float4 v = ((const float4*)W)[i];
  ushort4 hv; hv.x=f2bf(v.x); hv.y=f2bf(v.y); hv.z=f2bf(v.z); hv.w=f2bf(v.w);
  *(ushort4*)(Wbf + i*4) = hv;
}

// ---------------- 256x256 pipelined GEMM, static-index 4-deep pipeline ----------------
// BM=BN=256, BK=32. 512 threads = 8 waves (2 row-halves x 4 col-groups).
// LDS per tile: fg-blocked [4][256][8] bf16 per matrix (conflict-free b128 reads).
// 4 LDS buffers; stage 3 tiles ahead; buffer indices are COMPILE-TIME (x4 unroll);
// all LDS reads via inline asm => no compiler-inserted vmcnt drains; counted
// vmcnt(8/4/0) only at tile boundaries, lgkmcnt(4)/(0) inside.
template<int EPI, int SEGS, int NT>
__global__ __launch_bounds__(512, 2) void gemm256p(
    const u16* __restrict__ A0, const u16* __restrict__ A1, const u16* __restrict__ A2,
    const u16* __restrict__ B0, const u16* __restrict__ B1, const u16* __restrict__ B2,
    int lda0, int lda1, int lda2, int ldb,
    size_t sA0, size_t sA1, size_t sA2, size_t sB,
    void* __restrict__ outP, const float* __restrict__ bias)
{
  __shared__ __align__(16) u16 lds[4][2][8192];   // 128 KiB
  const int b = blockIdx.z;
  const int brow = blockIdx.y*256, bcol = blockIdx.x*256;
  const int tid = threadIdx.x;
  const int lane = tid & 63, wid = tid >> 6;
  const int wr = wid >> 2, wc = wid & 3;
  const int fr = lane & 15, fg = lane >> 4;

  const u16* a0p = A0 + (size_t)b*sA0 + (size_t)brow*lda0;
  const u16* a1p = (SEGS==3) ? (A1 + (size_t)b*sA1 + (size_t)brow*lda1) : a0p;
  const u16* a2p = (SEGS==3) ? (A2 + (size_t)b*sA2 + (size_t)brow*lda2) : a0p;
  const u16* b0p = B0 + (size_t)b*sB + (size_t)bcol*ldb;
  const u16* b1p = (SEGS==3) ? (B1 + (size_t)b*sB + (size_t)bcol*ldb) : b0p;
  const u16* b2p = (SEGS==3) ? (B2 + (size_t)b*sB + (size_t)bcol*ldb) : b0p;

  constexpr int SEGLEN = NT / SEGS;

  auto STAGE_TILE = [&](int tt){
    int sgi = (SEGS==1) ? 0 : (tt / SEGLEN);
    int kk  = (tt % SEGLEN) * 32;
    const u16* As = (sgi==0 ? a0p : (sgi==1 ? a1p : a2p)) + kk;
    int        la = (sgi==0 ? lda0 : (sgi==1 ? lda1 : lda2));
    const u16* Bs = (sgi==0 ? b0p : (sgi==1 ? b1p : b2p)) + kk;
    u16* dA = &lds[tt&3][0][0];
    u16* dB = &lds[tt&3][1][0];
#pragma unroll
    for (int it=0; it<2; ++it){
      int ub = it*512 + wid*64;
      int u  = ub + lane;
      int f8 = u >> 8, row = u & 255;
      gll16(As + (size_t)row*la + f8*8, dA + (size_t)ub*8);
    }
#pragma unroll
    for (int it=0; it<2; ++it){
      int ub = it*512 + wid*64;
      int u  = ub + lane;
      int f8 = u >> 8, row = u & 255;
      gll16(Bs + (size_t)row*ldb + f8*8, dB + (size_t)ub*8);
    }
  };

  f32x4 zero = {0.f,0.f,0.f,0.f};
  f32x4 acc[8][4];
#pragma unroll
  for (int m=0;m<8;++m)
#pragma unroll
    for (int n=0;n<4;++n) acc[m][n] = zero;

  // per-thread LDS byte bases (within buffer 0)
  const u32 lds0 = (u32)(uintptr_t)(las_ptr)&lds[0][0][0];
  const u32 aoff = lds0 + (u32)(fg*4096 + (wr*128+fr)*16);
  const u32 boff = lds0 + (u32)(16384 + fg*4096 + (wc*64+fr)*16);

  STAGE_TILE(0); STAGE_TILE(1); STAGE_TILE(2);
  asm volatile("s_waitcnt vmcnt(8)" ::: "memory");
  asm volatile("s_barrier" ::: "memory");
  __builtin_amdgcn_sched_barrier(0);

#define MM4(AV,M) \
  acc[M][0]=MFMA16(AV,bf0,acc[M][0]); acc[M][1]=MFMA16(AV,bf1,acc[M][1]); \
  acc[M][2]=MFMA16(AV,bf2,acc[M][2]); acc[M][3]=MFMA16(AV,bf3,acc[M][3]);

#define PIPE_ITER(J) { \
    const int t = tb + (J); \
    if (t+3 < NT) STAGE_TILE(t+3); \
    const u32 ab = aoff + (J)*32768u; \
    const u32 bb = boff + (J)*32768u; \
    short8 bf0 = dsr<0>(bb), bf1 = dsr<256>(bb), bf2 = dsr<512>(bb), bf3 = dsr<768>(bb); \
    short8 a0_ = dsr<0>(ab), a1_ = dsr<256>(ab), a2_ = dsr<512>(ab), a3_ = dsr<768>(ab); \
    short8 a4_ = dsr<1024>(ab), a5_ = dsr<1280>(ab), a6_ = dsr<1536>(ab), a7_ = dsr<1792>(ab); \
    asm volatile("s_waitcnt lgkmcnt(4)" ::: "memory"); \
    __builtin_amdgcn_sched_barrier(0); \
    __builtin_amdgcn_s_setprio(1); \
    MM4(a0_,0) MM4(a1_,1) MM4(a2_,2) MM4(a3_,3) \
    __builtin_amdgcn_s_setprio(0); \
    __builtin_amdgcn_sched_barrier(0); \
    asm volatile("s_waitcnt lgkmcnt(0)" ::: "memory"); \
    __builtin_amdgcn_sched_barrier(0); \
    __builtin_amdgcn_s_setprio(1); \
    MM4(a4_,4) MM4(a5_,5) MM4(a6_,6) MM4(a7_,7) \
    __builtin_amdgcn_s_setprio(0); \
    __builtin_amdgcn_sched_barrier(0); \
    if (t+3 < NT)      { asm volatile("s_waitcnt vmcnt(8)" ::: "memory"); } \
    else if (t+2 < NT) { asm volatile("s_waitcnt vmcnt(4)" ::: "memory"); } \
    else if (t+1 < NT) { asm volatile("s_waitcnt vmcnt(0)" ::: "memory"); } \
    asm volatile("s_barrier" ::: "memory"); \
    __builtin_amdgcn_sched_barrier(0); \
  }

#pragma unroll 1
  for (int tb = 0; tb < NT; tb += 4){
    PIPE_ITER(0)
    PIPE_ITER(1)
    PIPE_ITER(2)
    PIPE_ITER(3)
  }
#undef PIPE_ITER
#undef MM4

  // epilogue
  const int rbase = brow + wr*128;
  const int cbase = bcol + wc*64;
  if constexpr (EPI == 0){
    float* Ob = (float*)outP + (size_t)b*4194304;
#pragma unroll
    for (int mi=0;mi<8;++mi){
      int ro = (mi>>2)*64 + (mi&3)*16 + fg*4;
#pragma unroll
      for (int n=0;n<4;++n){
        int col = cbase + n*16 + fr;
#pragma unroll
        for (int r=0;r<4;++r)
          Ob[(size_t)(rbase + ro + r)*2048 + col] = acc[mi][n][r];
      }
    }
  } else if constexpr (EPI == 1){
    u16* Ob = (u16*)outP + (size_t)b*4194304;
#pragma unroll
    for (int mi=0;mi<8;++mi){
      int ro = (mi>>2)*64 + (mi&3)*16 + fg*4;
#pragma unroll
      for (int n=0;n<4;++n){
        int col = cbase + n*16 + fr;
#pragma unroll
        for (int r=0;r<4;++r)
          Ob[(size_t)(rbase + ro + r)*2048 + col] = f2bf(acc[mi][n][r]);
      }
    }
  } else {
    float* Ob = (float*)outP + (size_t)b*2097152;
#pragma unroll
    for (int mi=0;mi<8;++mi){
      int ro = (mi>>2)*64 + (mi&3)*16 + fg*4;
#pragma unroll
      for (int n=0;n<4;++n){
        int col = cbase + n*16 + fr;
        float bv = bias[col];
#pragma unroll
        for (int r=0;r<4;++r)
          Ob[(size_t)(rbase + ro + r)*1024 + col] = tanhf(acc[mi][n][r] + bv);
      }
    }
  }
}

// ---------------- masked row softmax (in place) + bf16 P copy ----------------
__global__ __launch_bounds__(256) void softmax_rows(float* __restrict__ S, const void* __restrict__ maskp,
                                                    u16* __restrict__ Pbf){
  __shared__ float red[4];
  __shared__ int s_is8;
  const int row = blockIdx.x;
  const int b = row >> 11;
  const int t = threadIdx.x;
  if (t == 0){
    const u32* mw0 = (const u32*)maskp;
    u32 accu = 0;
#pragma unroll
    for (int i = 0; i < 32; ++i) accu |= mw0[i];
    s_is8 = (accu & 0xffffff00u) ? 1 : 0;
  }
  float* Sr = S + (size_t)row * 2048;
  float4 s0 = ((const float4*)Sr)[t];
  float4 s1 = ((const float4*)Sr)[t + 256];
  __syncthreads();
  const int is8 = s_is8;
  float v[8] = {s0.x,s0.y,s0.z,s0.w, s1.x,s1.y,s1.z,s1.w};
  const unsigned char* mb = (const unsigned char*)maskp + (size_t)b*2048;
  const int* mw = (const int*)maskp + (size_t)b*2048;
  const int kb0 = t*4, kb1 = t*4 + 1024;
  const float NINF = -__builtin_inff();
#pragma unroll
  for (int j=0;j<4;++j){
    int m0 = is8 ? (int)mb[kb0+j] : mw[kb0+j];
    int m1 = is8 ? (int)mb[kb1+j] : mw[kb1+j];
    if (m0) v[j]   = NINF;
    if (m1) v[4+j] = NINF;
  }
  float m = v[0];
#pragma unroll
  for (int j=1;j<8;++j) m = fmaxf(m, v[j]);
  m = wredmax(m);
  if ((t & 63) == 0) red[t>>6] = m;
  __syncthreads();
  float M = fmaxf(fmaxf(red[0],red[1]), fmaxf(red[2],red[3]));
  __syncthreads();
  float e[8]; float sum = 0.f;
#pragma unroll
  for (int j=0;j<8;++j){ e[j] = __expf(v[j]-M); sum += e[j]; }
  sum = wredsum(sum);
  if ((t & 63) == 0) red[t>>6] = sum;
  __syncthreads();
  float L = red[0]+red[1]+red[2]+red[3];
  float inv = 1.0f / L;
  float o[8];
#pragma unroll
  for (int j=0;j<8;++j) o[j] = e[j]*inv;
  float4 o0 = {o[0],o[1],o[2],o[3]};
  float4 o1 = {o[4],o[5],o[6],o[7]};
  ((float4*)Sr)[t] = o0;
  ((float4*)Sr)[t+256] = o1;
  u16* Pr = Pbf + (size_t)row * 2048;
  ushort4 p0; p0.x=f2bf(o[0]); p0.y=f2bf(o[1]); p0.z=f2bf(o[2]); p0.w=f2bf(o[3]);
  ushort4 p1; p1.x=f2bf(o[4]); p1.y=f2bf(o[5]); p1.z=f2bf(o[6]); p1.w=f2bf(o[7]);
  *(ushort4*)(Pr + kb0) = p0;
  *(ushort4*)(Pr + kb1) = p1;
}

// ---------------- launch ----------------
extern "C" void kernel_launch(void* const* d_in, const int* in_sizes, int n_in,
                              void* d_out, int out_size, void* d_ws, size_t ws_size,
                              hipStream_t stream) {
  (void)in_sizes; (void)n_in; (void)out_size;
  const float* Q    = (const float*)d_in[0];
  const float* C    = (const float*)d_in[1];
  const void*  mask = d_in[2];
  const float* W    = (const float*)d_in[3];
  const float* bias = (const float*)d_in[4];
  float* out_f = (float*)d_out;

  // ws layout (bytes): CB 134217728 | Qlo 67108864 | CT 67108864 | Wbf 4194304
  if (ws_size < 272629760ull) return;
  u16* CB  = (u16*)d_ws;
  u16* Qlo = (u16*)((char*)d_ws + 134217728);
  u16* CT  = (u16*)((char*)d_ws + 201326592);
  u16* Wbf = (u16*)((char*)d_ws + 268435456);

  // d_out[0:134M) holds Chi+Clo during QK^T, then Pbf after softmax, finally Out.
  u16* Chi = (u16*)d_out;
  u16* Clo = Chi + 33554432;
  u16* Pbf = (u16*)d_out;
  float* S = out_f + 33554432;

  conv_q<<<32768, 256, 0, stream>>>(Q, CB, Qlo);
  conv_c<<<dim3(16,32,16), 256, 0, stream>>>(C, Chi, Clo, CT);
  conv_w<<<2048, 256, 0, stream>>>(W, Wbf);

  // K1: S = Qhi.Chi^T + Qhi.Clo^T + Qlo.Chi^T  (virtual K=3072, 3 segments)
  gemm256p<0,3,96><<<dim3(8,8,16), 512, 0, stream>>>(
      CB + 1024, CB + 1024, Qlo,
      Chi, Clo, Chi,
      2048, 2048, 1024, 1024,
      (size_t)4194304, (size_t)4194304, (size_t)2097152, (size_t)2097152,
      S, nullptr);

  softmax_rows<<<32768, 256, 0, stream>>>(S, mask, Pbf);

  // K3: mix = Pbf . CT^T -> bf16 into CB cols [0,1024)
  gemm256p<1,1,64><<<dim3(4,8,16), 512, 0, stream>>>(
      Pbf, nullptr, nullptr,
      CT, nullptr, nullptr,
      2048, 0, 0, 2048,
      (size_t)4194304, 0, 0, (size_t)2097152,
      CB, nullptr);

  // K4: out = tanh(CB . Wbf^T + bias)
  gemm256p<2,1,64><<<dim3(4,8,16), 512, 0, stream>>>(
      CB, nullptr, nullptr,
      Wbf, nullptr, nullptr,
      2048, 0, 0, 2048,
      (size_t)4194304, 0, 0, (size_t)0,
      out_f, bias);
}

// Round 4
// 1468.521 us; speedup vs baseline: 1.0427x; 1.0427x over previous
//
#include <hip/hip_runtime.h>

typedef __attribute__((ext_vector_type(8))) short short8;
typedef __attribute__((ext_vector_type(4))) float f32x4;
typedef unsigned short u16;
typedef unsigned int u32;

#define NB   16
#define NLQ  2048
#define NLK  2048
#define NH   1024

// ---------------- helpers ----------------
__device__ __forceinline__ u16 f2bf(float x){
  u32 u = __float_as_uint(x);
  return (u16)((u + 0x7fffu + ((u >> 16) & 1u)) >> 16);
}
__device__ __forceinline__ float bf2f(u16 h){ return __uint_as_float(((u32)h) << 16); }

__device__ __forceinline__ void split_bf(float x, u16& hi, u16& lo){
  u16 h = f2bf(x);
  float r = x - bf2f(h);
  hi = h; lo = f2bf(r);
}

typedef const __attribute__((address_space(1))) void* gas_ptr;
typedef __attribute__((address_space(3))) void* las_ptr;

__device__ __forceinline__ void gll16(const void* g, void* l){
  __builtin_amdgcn_global_load_lds((gas_ptr)g, (las_ptr)l, 16, 0, 0);
}

// stage 128x32 bf16 tile (row-major, ld in elems) -> LDS fg-blocked [4][128][8]
// (unit u: f8 = u>>7 selects k-group, row = u&127; dest linear, src permuted.
//  frag reads are then conflict-free: 16 consecutive fr-rows = 256 B stripe.)
__device__ __forceinline__ void stage_bf(const u16* __restrict__ src, int ld, u16* lds){
  const int lane = threadIdx.x & 63, wid = threadIdx.x >> 6;
#pragma unroll
  for (int t = 0; t < 2; ++t){
    int ub = t*256 + wid*64;     // wave-uniform 16B-unit base
    int u  = ub + lane;
    int f8 = u >> 7;             // k-group 0..3
    int r  = u & 127;            // row 0..127
    gll16(src + (size_t)r*ld + f8*8, lds + (size_t)ub*8);
  }
}

__device__ __forceinline__ short8 frag_bf(const u16* lds, int row, int fg){
  return *(const short8*)(lds + (size_t)fg*1024 + (size_t)row*8);
}

#define MFMA16(a,b,c) __builtin_amdgcn_mfma_f32_16x16x32_bf16((a),(b),(c),0,0,0)

__device__ __forceinline__ float wredmax(float v){
#pragma unroll
  for (int off = 32; off > 0; off >>= 1) v = fmaxf(v, __shfl_xor(v, off, 64));
  return v;
}
__device__ __forceinline__ float wredsum(float v){
#pragma unroll
  for (int off = 32; off > 0; off >>= 1) v += __shfl_xor(v, off, 64);
  return v;
}

// ---------------- converts ----------------
// Q [B,LQ,H] f32 -> CB[:, :, 1024:2048] = Qhi (row stride 2048), Qlo [B,LQ,H]
__global__ void conv_q(const float* __restrict__ Q, u16* __restrict__ CB, u16* __restrict__ Qlo){
  size_t i = (size_t)blockIdx.x*256 + threadIdx.x;
  float4 v = ((const float4*)Q)[i];
  size_t e = i*4;
  size_t row = e >> 10;
  int h = (int)(e & 1023);
  u16 h0,h1,h2,h3,l0,l1,l2,l3;
  split_bf(v.x,h0,l0); split_bf(v.y,h1,l1); split_bf(v.z,h2,l2); split_bf(v.w,h3,l3);
  ushort4 hv; hv.x=h0; hv.y=h1; hv.z=h2; hv.w=h3;
  ushort4 lv; lv.x=l0; lv.y=l1; lv.z=l2; lv.w=l3;
  *(ushort4*)(CB + row*2048 + 1024 + h) = hv;
  *(ushort4*)(Qlo + row*1024 + h) = lv;
}

// C [B,LK,H] f32 -> Chi,Clo [B,LK,H] bf16 ; CT [B,H,LK] bf16 (hi only)
__global__ void conv_c(const float* __restrict__ C, u16* __restrict__ Chi,
                       u16* __restrict__ Clo, u16* __restrict__ CT){
  __shared__ u16 tile[64][65];
  const int b = blockIdx.z;
  const int k0 = blockIdx.y*64, h0 = blockIdx.x*64;
  const float* Cb = C + ((size_t)b*NLK + k0)*NH + h0;
  const int t = threadIdx.x;
#pragma unroll
  for (int i = 0; i < 4; ++i){
    int q = i*256 + t;
    int r = q >> 4;
    int c4 = (q & 15) * 4;
    float4 v = *(const float4*)(Cb + (size_t)r*NH + c4);
    u16 h0_,h1_,h2_,h3_,l0_,l1_,l2_,l3_;
    split_bf(v.x,h0_,l0_); split_bf(v.y,h1_,l1_); split_bf(v.z,h2_,l2_); split_bf(v.w,h3_,l3_);
    size_t base = ((size_t)b*NLK + k0 + r)*NH + h0 + c4;
    ushort4 hv; hv.x=h0_; hv.y=h1_; hv.z=h2_; hv.w=h3_;
    ushort4 lv; lv.x=l0_; lv.y=l1_; lv.z=l2_; lv.w=l3_;
    *(ushort4*)(Chi + base) = hv;
    *(ushort4*)(Clo + base) = lv;
    tile[r][c4+0]=h0_; tile[r][c4+1]=h1_; tile[r][c4+2]=h2_; tile[r][c4+3]=h3_;
  }
  __syncthreads();
#pragma unroll
  for (int i = 0; i < 4; ++i){
    int q = i*256 + t;
    int hl = q >> 4;
    int k4 = (q & 15) * 4;
    ushort4 o;
    o.x = tile[k4+0][hl]; o.y = tile[k4+1][hl]; o.z = tile[k4+2][hl]; o.w = tile[k4+3][hl];
    *(ushort4*)(CT + ((size_t)b*NH + h0 + hl)*NLK + k0 + k4) = o;
  }
}

// W [H,2H] f32 -> bf16
__global__ void conv_w(const float* __restrict__ W, u16* __restrict__ Wbf){
  size_t i = (size_t)blockIdx.x*256 + threadIdx.x;
  float4 v = ((const float4*)W)[i];
  ushort4 hv; hv.x=f2bf(v.x); hv.y=f2bf(v.y); hv.z=f2bf(v.z); hv.w=f2bf(v.w);
  *(ushort4*)(Wbf + i*4) = hv;
}

// ---------------- K1: S = Q . C^T  (bf16 hi/lo split, 3 MFMA, fused segs) ----------------
__global__ __launch_bounds__(256,2) void k1_scores(
    const u16* __restrict__ Qhi, const u16* __restrict__ Qlo,
    const u16* __restrict__ Chi, const u16* __restrict__ Clo,
    float* __restrict__ S)
{
  __shared__ __align__(16) u16 sAh[4096], sAl[4096], sBh[4096], sBl[4096];
  const int b = blockIdx.z;
  const int brow = blockIdx.y*128, bcol = blockIdx.x*128;
  const u16* Ah = Qhi + (size_t)b*4194304 + (size_t)brow*2048;  // CB upper half, ld 2048
  const u16* Al = Qlo + (size_t)b*2097152 + (size_t)brow*1024;
  const u16* Bh = Chi + (size_t)b*2097152 + (size_t)bcol*1024;
  const u16* Bl = Clo + (size_t)b*2097152 + (size_t)bcol*1024;
  const int lane = threadIdx.x & 63, wid = threadIdx.x >> 6;
  const int wr = wid >> 1, wc = wid & 1;
  const int fr = lane & 15, fg = lane >> 4;
  f32x4 zero = {0.f,0.f,0.f,0.f};
  f32x4 acc[4][4];
#pragma unroll
  for (int m=0;m<4;++m)
#pragma unroll
    for (int n=0;n<4;++n) acc[m][n] = zero;

  for (int k0 = 0; k0 < 1024; k0 += 32){
    __syncthreads();
    stage_bf(Ah + k0, 2048, sAh);
    stage_bf(Al + k0, 1024, sAl);
    stage_bf(Bh + k0, 1024, sBh);
    stage_bf(Bl + k0, 1024, sBl);
    __syncthreads();
    short8 a[4], al[4], bh[4], bl[4];
#pragma unroll
    for (int m=0;m<4;++m){
      int r = wr*64 + m*16 + fr;
      a[m]  = frag_bf(sAh, r, fg);
      al[m] = frag_bf(sAl, r, fg);
    }
#pragma unroll
    for (int n=0;n<4;++n){
      int r = wc*64 + n*16 + fr;
      bh[n] = frag_bf(sBh, r, fg);
      bl[n] = frag_bf(sBl, r, fg);
    }
#pragma unroll
    for (int m=0;m<4;++m)
#pragma unroll
      for (int n=0;n<4;++n){
        acc[m][n] = MFMA16(a[m],  bh[n], acc[m][n]);
        acc[m][n] = MFMA16(a[m],  bl[n], acc[m][n]);
        acc[m][n] = MFMA16(al[m], bh[n], acc[m][n]);
      }
  }
  float* Sb = S + (size_t)b*4194304;
#pragma unroll
  for (int m=0;m<4;++m)
#pragma unroll
    for (int n=0;n<4;++n){
      int col  = bcol + wc*64 + n*16 + fr;
      int rowb = brow + wr*64 + m*16 + fg*4;
#pragma unroll
      for (int r4=0;r4<4;++r4)
        Sb[(size_t)(rowb + r4)*2048 + col] = acc[m][n][r4];
    }
}

// ---------------- K2: in-place masked row softmax + bf16 P ----------------
__global__ __launch_bounds__(256) void softmax_rows(float* __restrict__ S, const void* __restrict__ maskp,
                                                    u16* __restrict__ Pbf){
  __shared__ float red[4];
  __shared__ int s_is8;
  const int row = blockIdx.x;
  const int b = row >> 11;
  const int t = threadIdx.x;
  if (t == 0){
    const u32* mw0 = (const u32*)maskp;
    u32 accu = 0;
#pragma unroll
    for (int i = 0; i < 32; ++i) accu |= mw0[i];
    s_is8 = (accu & 0xffffff00u) ? 1 : 0;   // byte-packed bools if high bytes populated
  }
  float* Sr = S + (size_t)row * 2048;
  float4 s0 = ((const float4*)Sr)[t];
  float4 s1 = ((const float4*)Sr)[t + 256];
  __syncthreads();
  const int is8 = s_is8;
  float v[8] = {s0.x,s0.y,s0.z,s0.w, s1.x,s1.y,s1.z,s1.w};
  const unsigned char* mb = (const unsigned char*)maskp + (size_t)b*2048;
  const int* mw = (const int*)maskp + (size_t)b*2048;
  const int kb0 = t*4, kb1 = t*4 + 1024;
  const float NINF = -__builtin_inff();
#pragma unroll
  for (int j=0;j<4;++j){
    int m0 = is8 ? (int)mb[kb0+j] : mw[kb0+j];
    int m1 = is8 ? (int)mb[kb1+j] : mw[kb1+j];
    if (m0) v[j]   = NINF;
    if (m1) v[4+j] = NINF;
  }
  float m = v[0];
#pragma unroll
  for (int j=1;j<8;++j) m = fmaxf(m, v[j]);
  m = wredmax(m);
  if ((t & 63) == 0) red[t>>6] = m;
  __syncthreads();
  float M = fmaxf(fmaxf(red[0],red[1]), fmaxf(red[2],red[3]));
  __syncthreads();
  float e[8]; float sum = 0.f;
#pragma unroll
  for (int j=0;j<8;++j){ e[j] = __expf(v[j]-M); sum += e[j]; }
  sum = wredsum(sum);
  if ((t & 63) == 0) red[t>>6] = sum;
  __syncthreads();
  float L = red[0]+red[1]+red[2]+red[3];
  float inv = 1.0f / L;
  float o[8];
#pragma unroll
  for (int j=0;j<8;++j) o[j] = e[j]*inv;
  float4 o0 = {o[0],o[1],o[2],o[3]};
  float4 o1 = {o[4],o[5],o[6],o[7]};
  ((float4*)Sr)[t] = o0;
  ((float4*)Sr)[t+256] = o1;
  u16* Pr = Pbf + (size_t)row * 2048;
  ushort4 p0; p0.x=f2bf(o[0]); p0.y=f2bf(o[1]); p0.z=f2bf(o[2]); p0.w=f2bf(o[3]);
  ushort4 p1; p1.x=f2bf(o[4]); p1.y=f2bf(o[5]); p1.z=f2bf(o[6]); p1.w=f2bf(o[7]);
  *(ushort4*)(Pr + kb0) = p0;
  *(ushort4*)(Pr + kb1) = p1;
}

// ---------------- K3: mix = Pbf . CT^T -> bf16 into CB[:, :, 0:1024] ----------------
__global__ __launch_bounds__(256,2) void k3_mix(
    const u16* __restrict__ Pbf, const u16* __restrict__ CT, u16* __restrict__ CB)
{
  __shared__ __align__(16) u16 sA[4096], sB[4096];
  const int b = blockIdx.z;
  const int brow = blockIdx.y*128, bcol = blockIdx.x*128;  // bcol over H
  const u16* Ap = Pbf + (size_t)b*4194304 + (size_t)brow*2048;
  const u16* Bp = CT  + (size_t)b*2097152 + (size_t)bcol*2048;
  const int lane = threadIdx.x & 63, wid = threadIdx.x >> 6;
  const int wr = wid >> 1, wc = wid & 1;
  const int fr = lane & 15, fg = lane >> 4;
  f32x4 zero = {0.f,0.f,0.f,0.f};
  f32x4 acc[4][4];
#pragma unroll
  for (int m=0;m<4;++m)
#pragma unroll
    for (int n=0;n<4;++n) acc[m][n] = zero;

  for (int k0 = 0; k0 < 2048; k0 += 32){
    __syncthreads();
    stage_bf(Ap + k0, 2048, sA);
    stage_bf(Bp + k0, 2048, sB);
    __syncthreads();
    short8 a[4], bb[4];
#pragma unroll
    for (int m=0;m<4;++m) a[m] = frag_bf(sA, wr*64 + m*16 + fr, fg);
#pragma unroll
    for (int n=0;n<4;++n) bb[n] = frag_bf(sB, wc*64 + n*16 + fr, fg);
#pragma unroll
    for (int m=0;m<4;++m)
#pragma unroll
      for (int n=0;n<4;++n)
        acc[m][n] = MFMA16(a[m], bb[n], acc[m][n]);
  }
  u16* Ob = CB + (size_t)b*4194304;
#pragma unroll
  for (int m=0;m<4;++m)
#pragma unroll
    for (int n=0;n<4;++n){
      int col  = bcol + wc*64 + n*16 + fr;       // < 1024
      int rowb = brow + wr*64 + m*16 + fg*4;
#pragma unroll
      for (int r4=0;r4<4;++r4)
        Ob[(size_t)(rowb + r4)*2048 + col] = f2bf(acc[m][n][r4]);
    }
}

// ---------------- K4: out = tanh(CB . W^T + b) ----------------
__global__ __launch_bounds__(256,2) void k4_out(
    const u16* __restrict__ CB, const u16* __restrict__ Wbf,
    const float* __restrict__ bias, float* __restrict__ Out)
{
  __shared__ __align__(16) u16 sA[4096], sB[4096];
  const int b = blockIdx.z;
  const int brow = blockIdx.y*128, bcol = blockIdx.x*128;  // bcol over H out
  const u16* Ap = CB  + (size_t)b*4194304 + (size_t)brow*2048;
  const u16* Bp = Wbf + (size_t)bcol*2048;
  const int lane = threadIdx.x & 63, wid = threadIdx.x >> 6;
  const int wr = wid >> 1, wc = wid & 1;
  const int fr = lane & 15, fg = lane >> 4;
  f32x4 zero = {0.f,0.f,0.f,0.f};
  f32x4 acc[4][4];
#pragma unroll
  for (int m=0;m<4;++m)
#pragma unroll
    for (int n=0;n<4;++n) acc[m][n] = zero;

  for (int k0 = 0; k0 < 2048; k0 += 32){
    __syncthreads();
    stage_bf(Ap + k0, 2048, sA);
    stage_bf(Bp + k0, 2048, sB);
    __syncthreads();
    short8 a[4], bb[4];
#pragma unroll
    for (int m=0;m<4;++m) a[m] = frag_bf(sA, wr*64 + m*16 + fr, fg);
#pragma unroll
    for (int n=0;n<4;++n) bb[n] = frag_bf(sB, wc*64 + n*16 + fr, fg);
#pragma unroll
    for (int m=0;m<4;++m)
#pragma unroll
      for (int n=0;n<4;++n)
        acc[m][n] = MFMA16(a[m], bb[n], acc[m][n]);
  }
  float* Ob = Out + (size_t)b*2097152;
#pragma unroll
  for (int m=0;m<4;++m)
#pragma unroll
    for (int n=0;n<4;++n){
      int col  = bcol + wc*64 + n*16 + fr;
      float bv = bias[col];
      int rowb = brow + wr*64 + m*16 + fg*4;
#pragma unroll
      for (int r4=0;r4<4;++r4)
        Ob[(size_t)(rowb + r4)*1024 + col] = tanhf(acc[m][n][r4] + bv);
    }
}

// ---------------- launch ----------------
extern "C" void kernel_launch(void* const* d_in, const int* in_sizes, int n_in,
                              void* d_out, int out_size, void* d_ws, size_t ws_size,
                              hipStream_t stream) {
  (void)in_sizes; (void)n_in; (void)out_size;
  const float* Q    = (const float*)d_in[0];
  const float* C    = (const float*)d_in[1];
  const void*  mask = d_in[2];
  const float* W    = (const float*)d_in[3];
  const float* bias = (const float*)d_in[4];
  float* out_f = (float*)d_out;

  // ws layout (bytes): CB 134217728 | Qlo 67108864 | CT 67108864 | Wbf 4194304
  if (ws_size < 272629760ull) return;
  u16* CB  = (u16*)d_ws;
  u16* Qlo = (u16*)((char*)d_ws + 134217728);
  u16* CT  = (u16*)((char*)d_ws + 201326592);
  u16* Wbf = (u16*)((char*)d_ws + 268435456);

  // d_out[0:134M) holds Chi+Clo during K1, then Pbf after softmax, finally Out.
  u16* Chi = (u16*)d_out;
  u16* Clo = Chi + 33554432;
  u16* Pbf = (u16*)d_out;
  float* S = out_f + 33554432;   // attn region: raw scores -> probs in place

  conv_q<<<32768, 256, 0, stream>>>(Q, CB, Qlo);
  conv_c<<<dim3(16,32,16), 256, 0, stream>>>(C, Chi, Clo, CT);
  conv_w<<<2048, 256, 0, stream>>>(W, Wbf);

  k1_scores<<<dim3(16,16,16), 256, 0, stream>>>(CB + 1024, Qlo, Chi, Clo, S);

  softmax_rows<<<32768, 256, 0, stream>>>(S, mask, Pbf);

  k3_mix<<<dim3(8,16,16), 256, 0, stream>>>(Pbf, CT, CB);

  k4_out<<<dim3(8,16,16), 256, 0, stream>>>(CB, Wbf, bias, out_f);
}

// Round 5
// 982.615 us; speedup vs baseline: 1.5584x; 1.4945x over previous
//
#include <hip/hip_runtime.h>

typedef __attribute__((ext_vector_type(8))) short short8;
typedef __attribute__((ext_vector_type(4))) float f32x4;
typedef unsigned short u16;
typedef unsigned int u32;

#define NB   16
#define NLQ  2048
#define NLK  2048
#define NH   1024

// ---------------- helpers ----------------
__device__ __forceinline__ u16 f2bf(float x){
  u32 u = __float_as_uint(x);
  return (u16)((u + 0x7fffu + ((u >> 16) & 1u)) >> 16);
}
__device__ __forceinline__ float bf2f(u16 h){ return __uint_as_float(((u32)h) << 16); }

__device__ __forceinline__ void split_bf(float x, u16& hi, u16& lo){
  u16 h = f2bf(x);
  float r = x - bf2f(h);
  hi = h; lo = f2bf(r);
}

typedef const __attribute__((address_space(1))) void* gas_ptr;
typedef __attribute__((address_space(3))) void* las_ptr;

__device__ __forceinline__ void gll16(const void* g, void* l){
  __builtin_amdgcn_global_load_lds((gas_ptr)g, (las_ptr)l, 16, 0, 0);
}

// stage 128x32 bf16 tile (row-major, ld in elems) -> LDS [128][4 slots of 16B]
// with slot swizzle: LDS slot p of row r holds source slot p ^ ((r>>1)&3).
// Source side: 4 lanes per row cover the same 64B contiguous segment (coalesced);
// read side: frag(row,fg) at slot fg^((row>>1)&3) spreads 16 fr-lanes over all
// 8 bank-quads (2 lanes each = conflict-free).
__device__ __forceinline__ void stage_bf(const u16* __restrict__ src, int ld, u16* lds){
  const int lane = threadIdx.x & 63, wid = threadIdx.x >> 6;
#pragma unroll
  for (int t = 0; t < 2; ++t){
    int ub = t*256 + wid*64;     // wave-uniform 16B-unit base
    int u  = ub + lane;
    int r  = u >> 2;             // row 0..127
    int s  = (u & 3) ^ ((r >> 1) & 3);  // pre-swizzled source slot
    gll16(src + (size_t)r*ld + s*8, lds + (size_t)ub*8);
  }
}

__device__ __forceinline__ short8 frag_bf(const u16* lds, int row, int fg){
  int p = fg ^ ((row >> 1) & 3);
  return *(const short8*)(lds + (size_t)row*32 + p*8);
}

#define MFMA16(a,b,c) __builtin_amdgcn_mfma_f32_16x16x32_bf16((a),(b),(c),0,0,0)

__device__ __forceinline__ float wredmax(float v){
#pragma unroll
  for (int off = 32; off > 0; off >>= 1) v = fmaxf(v, __shfl_xor(v, off, 64));
  return v;
}
__device__ __forceinline__ float wredsum(float v){
#pragma unroll
  for (int off = 32; off > 0; off >>= 1) v += __shfl_xor(v, off, 64);
  return v;
}

// ---------------- converts ----------------
// Q [B,LQ,H] f32 -> CB[:, :, 1024:2048] = Qhi (row stride 2048), Qlo [B,LQ,H]
__global__ void conv_q(const float* __restrict__ Q, u16* __restrict__ CB, u16* __restrict__ Qlo){
  size_t i = (size_t)blockIdx.x*256 + threadIdx.x;
  float4 v = ((const float4*)Q)[i];
  size_t e = i*4;
  size_t row = e >> 10;
  int h = (int)(e & 1023);
  u16 h0,h1,h2,h3,l0,l1,l2,l3;
  split_bf(v.x,h0,l0); split_bf(v.y,h1,l1); split_bf(v.z,h2,l2); split_bf(v.w,h3,l3);
  ushort4 hv; hv.x=h0; hv.y=h1; hv.z=h2; hv.w=h3;
  ushort4 lv; lv.x=l0; lv.y=l1; lv.z=l2; lv.w=l3;
  *(ushort4*)(CB + row*2048 + 1024 + h) = hv;
  *(ushort4*)(Qlo + row*1024 + h) = lv;
}

// C [B,LK,H] f32 -> Chi,Clo [B,LK,H] bf16 ; CT [B,H,LK] bf16 (hi only)
__global__ void conv_c(const float* __restrict__ C, u16* __restrict__ Chi,
                       u16* __restrict__ Clo, u16* __restrict__ CT){
  __shared__ u16 tile[64][65];
  const int b = blockIdx.z;
  const int k0 = blockIdx.y*64, h0 = blockIdx.x*64;
  const float* Cb = C + ((size_t)b*NLK + k0)*NH + h0;
  const int t = threadIdx.x;
#pragma unroll
  for (int i = 0; i < 4; ++i){
    int q = i*256 + t;
    int r = q >> 4;
    int c4 = (q & 15) * 4;
    float4 v = *(const float4*)(Cb + (size_t)r*NH + c4);
    u16 h0_,h1_,h2_,h3_,l0_,l1_,l2_,l3_;
    split_bf(v.x,h0_,l0_); split_bf(v.y,h1_,l1_); split_bf(v.z,h2_,l2_); split_bf(v.w,h3_,l3_);
    size_t base = ((size_t)b*NLK + k0 + r)*NH + h0 + c4;
    ushort4 hv; hv.x=h0_; hv.y=h1_; hv.z=h2_; hv.w=h3_;
    ushort4 lv; lv.x=l0_; lv.y=l1_; lv.z=l2_; lv.w=l3_;
    *(ushort4*)(Chi + base) = hv;
    *(ushort4*)(Clo + base) = lv;
    tile[r][c4+0]=h0_; tile[r][c4+1]=h1_; tile[r][c4+2]=h2_; tile[r][c4+3]=h3_;
  }
  __syncthreads();
#pragma unroll
  for (int i = 0; i < 4; ++i){
    int q = i*256 + t;
    int hl = q >> 4;
    int k4 = (q & 15) * 4;
    ushort4 o;
    o.x = tile[k4+0][hl]; o.y = tile[k4+1][hl]; o.z = tile[k4+2][hl]; o.w = tile[k4+3][hl];
    *(ushort4*)(CT + ((size_t)b*NH + h0 + hl)*NLK + k0 + k4) = o;
  }
}

// W [H,2H] f32 -> bf16
__global__ void conv_w(const float* __restrict__ W, u16* __restrict__ Wbf){
  size_t i = (size_t)blockIdx.x*256 + threadIdx.x;
  float4 v = ((const float4*)W)[i];
  ushort4 hv; hv.x=f2bf(v.x); hv.y=f2bf(v.y); hv.z=f2bf(v.z); hv.w=f2bf(v.w);
  *(ushort4*)(Wbf + i*4) = hv;
}

// ---------------- K1: S = Q . C^T  (bf16 hi/lo split, 3 MFMA, fused segs) ----------------
// 1D grid 4096, XCD-swizzled: each XCD owns 2 batches; bcol fastest (A-panel L2-resident).
__global__ __launch_bounds__(256,2) void k1_scores(
    const u16* __restrict__ Qhi, const u16* __restrict__ Qlo,
    const u16* __restrict__ Chi, const u16* __restrict__ Clo,
    float* __restrict__ S)
{
  __shared__ __align__(16) u16 sAh[4096], sAl[4096], sBh[4096], sBl[4096];
  const u32 lin = blockIdx.x;
  const u32 swz = (lin & 7u)*512u + (lin >> 3);
  const int bcol = (int)(swz & 15u) * 128;
  const int brow = (int)((swz >> 4) & 15u) * 128;
  const int b    = (int)(swz >> 8);
  const u16* Ah = Qhi + (size_t)b*4194304 + (size_t)brow*2048;  // CB upper half, ld 2048
  const u16* Al = Qlo + (size_t)b*2097152 + (size_t)brow*1024;
  const u16* Bh = Chi + (size_t)b*2097152 + (size_t)bcol*1024;
  const u16* Bl = Clo + (size_t)b*2097152 + (size_t)bcol*1024;
  const int lane = threadIdx.x & 63, wid = threadIdx.x >> 6;
  const int wr = wid >> 1, wc = wid & 1;
  const int fr = lane & 15, fg = lane >> 4;
  f32x4 zero = {0.f,0.f,0.f,0.f};
  f32x4 acc[4][4];
#pragma unroll
  for (int m=0;m<4;++m)
#pragma unroll
    for (int n=0;n<4;++n) acc[m][n] = zero;

  for (int k0 = 0; k0 < 1024; k0 += 32){
    __syncthreads();
    stage_bf(Ah + k0, 2048, sAh);
    stage_bf(Al + k0, 1024, sAl);
    stage_bf(Bh + k0, 1024, sBh);
    stage_bf(Bl + k0, 1024, sBl);
    __syncthreads();
    short8 a[4], al[4], bh[4], bl[4];
#pragma unroll
    for (int m=0;m<4;++m){
      int r = wr*64 + m*16 + fr;
      a[m]  = frag_bf(sAh, r, fg);
      al[m] = frag_bf(sAl, r, fg);
    }
#pragma unroll
    for (int n=0;n<4;++n){
      int r = wc*64 + n*16 + fr;
      bh[n] = frag_bf(sBh, r, fg);
      bl[n] = frag_bf(sBl, r, fg);
    }
#pragma unroll
    for (int m=0;m<4;++m)
#pragma unroll
      for (int n=0;n<4;++n){
        acc[m][n] = MFMA16(a[m],  bh[n], acc[m][n]);
        acc[m][n] = MFMA16(a[m],  bl[n], acc[m][n]);
        acc[m][n] = MFMA16(al[m], bh[n], acc[m][n]);
      }
  }
  float* Sb = S + (size_t)b*4194304;
#pragma unroll
  for (int m=0;m<4;++m)
#pragma unroll
    for (int n=0;n<4;++n){
      int col  = bcol + wc*64 + n*16 + fr;
      int rowb = brow + wr*64 + m*16 + fg*4;
#pragma unroll
      for (int r4=0;r4<4;++r4)
        Sb[(size_t)(rowb + r4)*2048 + col] = acc[m][n][r4];
    }
}

// ---------------- K2: in-place masked row softmax + bf16 P ----------------
__global__ __launch_bounds__(256) void softmax_rows(float* __restrict__ S, const void* __restrict__ maskp,
                                                    u16* __restrict__ Pbf){
  __shared__ float red[4];
  __shared__ int s_is8;
  const int row = blockIdx.x;
  const int b = row >> 11;
  const int t = threadIdx.x;
  if (t == 0){
    const u32* mw0 = (const u32*)maskp;
    u32 accu = 0;
#pragma unroll
    for (int i = 0; i < 32; ++i) accu |= mw0[i];
    s_is8 = (accu & 0xffffff00u) ? 1 : 0;   // byte-packed bools if high bytes populated
  }
  float* Sr = S + (size_t)row * 2048;
  float4 s0 = ((const float4*)Sr)[t];
  float4 s1 = ((const float4*)Sr)[t + 256];
  __syncthreads();
  const int is8 = s_is8;
  float v[8] = {s0.x,s0.y,s0.z,s0.w, s1.x,s1.y,s1.z,s1.w};
  const unsigned char* mb = (const unsigned char*)maskp + (size_t)b*2048;
  const int* mw = (const int*)maskp + (size_t)b*2048;
  const int kb0 = t*4, kb1 = t*4 + 1024;
  const float NINF = -__builtin_inff();
#pragma unroll
  for (int j=0;j<4;++j){
    int m0 = is8 ? (int)mb[kb0+j] : mw[kb0+j];
    int m1 = is8 ? (int)mb[kb1+j] : mw[kb1+j];
    if (m0) v[j]   = NINF;
    if (m1) v[4+j] = NINF;
  }
  float m = v[0];
#pragma unroll
  for (int j=1;j<8;++j) m = fmaxf(m, v[j]);
  m = wredmax(m);
  if ((t & 63) == 0) red[t>>6] = m;
  __syncthreads();
  float M = fmaxf(fmaxf(red[0],red[1]), fmaxf(red[2],red[3]));
  __syncthreads();
  float e[8]; float sum = 0.f;
#pragma unroll
  for (int j=0;j<8;++j){ e[j] = __expf(v[j]-M); sum += e[j]; }
  sum = wredsum(sum);
  if ((t & 63) == 0) red[t>>6] = sum;
  __syncthreads();
  float L = red[0]+red[1]+red[2]+red[3];
  float inv = 1.0f / L;
  float o[8];
#pragma unroll
  for (int j=0;j<8;++j) o[j] = e[j]*inv;
  float4 o0 = {o[0],o[1],o[2],o[3]};
  float4 o1 = {o[4],o[5],o[6],o[7]};
  ((float4*)Sr)[t] = o0;
  ((float4*)Sr)[t+256] = o1;
  u16* Pr = Pbf + (size_t)row * 2048;
  ushort4 p0; p0.x=f2bf(o[0]); p0.y=f2bf(o[1]); p0.z=f2bf(o[2]); p0.w=f2bf(o[3]);
  ushort4 p1; p1.x=f2bf(o[4]); p1.y=f2bf(o[5]); p1.z=f2bf(o[6]); p1.w=f2bf(o[7]);
  *(ushort4*)(Pr + kb0) = p0;
  *(ushort4*)(Pr + kb1) = p1;
}

// ---------------- K3: mix = Pbf . CT^T -> bf16 into CB[:, :, 0:1024] ----------------
// 1D grid 2048, XCD-swizzled.
__global__ __launch_bounds__(256,2) void k3_mix(
    const u16* __restrict__ Pbf, const u16* __restrict__ CT, u16* __restrict__ CB)
{
  __shared__ __align__(16) u16 sA[4096], sB[4096];
  const u32 lin = blockIdx.x;
  const u32 swz = (lin & 7u)*256u + (lin >> 3);
  const int bcol = (int)(swz & 7u) * 128;          // over H
  const int brow = (int)((swz >> 3) & 15u) * 128;
  const int b    = (int)(swz >> 7);
  const u16* Ap = Pbf + (size_t)b*4194304 + (size_t)brow*2048;
  const u16* Bp = CT  + (size_t)b*2097152 + (size_t)bcol*2048;
  const int lane = threadIdx.x & 63, wid = threadIdx.x >> 6;
  const int wr = wid >> 1, wc = wid & 1;
  const int fr = lane & 15, fg = lane >> 4;
  f32x4 zero = {0.f,0.f,0.f,0.f};
  f32x4 acc[4][4];
#pragma unroll
  for (int m=0;m<4;++m)
#pragma unroll
    for (int n=0;n<4;++n) acc[m][n] = zero;

  for (int k0 = 0; k0 < 2048; k0 += 32){
    __syncthreads();
    stage_bf(Ap + k0, 2048, sA);
    stage_bf(Bp + k0, 2048, sB);
    __syncthreads();
    short8 a[4], bb[4];
#pragma unroll
    for (int m=0;m<4;++m) a[m] = frag_bf(sA, wr*64 + m*16 + fr, fg);
#pragma unroll
    for (int n=0;n<4;++n) bb[n] = frag_bf(sB, wc*64 + n*16 + fr, fg);
#pragma unroll
    for (int m=0;m<4;++m)
#pragma unroll
      for (int n=0;n<4;++n)
        acc[m][n] = MFMA16(a[m], bb[n], acc[m][n]);
  }
  u16* Ob = CB + (size_t)b*4194304;
#pragma unroll
  for (int m=0;m<4;++m)
#pragma unroll
    for (int n=0;n<4;++n){
      int col  = bcol + wc*64 + n*16 + fr;       // < 1024
      int rowb = brow + wr*64 + m*16 + fg*4;
#pragma unroll
      for (int r4=0;r4<4;++r4)
        Ob[(size_t)(rowb + r4)*2048 + col] = f2bf(acc[m][n][r4]);
    }
}

// ---------------- K4: out = tanh(CB . W^T + b) ----------------
// 1D grid 2048, XCD-swizzled.
__global__ __launch_bounds__(256,2) void k4_out(
    const u16* __restrict__ CB, const u16* __restrict__ Wbf,
    const float* __restrict__ bias, float* __restrict__ Out)
{
  __shared__ __align__(16) u16 sA[4096], sB[4096];
  const u32 lin = blockIdx.x;
  const u32 swz = (lin & 7u)*256u + (lin >> 3);
  const int bcol = (int)(swz & 7u) * 128;          // over H out
  const int brow = (int)((swz >> 3) & 15u) * 128;
  const int b    = (int)(swz >> 7);
  const u16* Ap = CB  + (size_t)b*4194304 + (size_t)brow*2048;
  const u16* Bp = Wbf + (size_t)bcol*2048;
  const int lane = threadIdx.x & 63, wid = threadIdx.x >> 6;
  const int wr = wid >> 1, wc = wid & 1;
  const int fr = lane & 15, fg = lane >> 4;
  f32x4 zero = {0.f,0.f,0.f,0.f};
  f32x4 acc[4][4];
#pragma unroll
  for (int m=0;m<4;++m)
#pragma unroll
    for (int n=0;n<4;++n) acc[m][n] = zero;

  for (int k0 = 0; k0 < 2048; k0 += 32){
    __syncthreads();
    stage_bf(Ap + k0, 2048, sA);
    stage_bf(Bp + k0, 2048, sB);
    __syncthreads();
    short8 a[4], bb[4];
#pragma unroll
    for (int m=0;m<4;++m) a[m] = frag_bf(sA, wr*64 + m*16 + fr, fg);
#pragma unroll
    for (int n=0;n<4;++n) bb[n] = frag_bf(sB, wc*64 + n*16 + fr, fg);
#pragma unroll
    for (int m=0;m<4;++m)
#pragma unroll
      for (int n=0;n<4;++n)
        acc[m][n] = MFMA16(a[m], bb[n], acc[m][n]);
  }
  float* Ob = Out + (size_t)b*2097152;
#pragma unroll
  for (int m=0;m<4;++m)
#pragma unroll
    for (int n=0;n<4;++n){
      int col  = bcol + wc*64 + n*16 + fr;
      float bv = bias[col];
      int rowb = brow + wr*64 + m*16 + fg*4;
#pragma unroll
      for (int r4=0;r4<4;++r4)
        Ob[(size_t)(rowb + r4)*1024 + col] = tanhf(acc[m][n][r4] + bv);
    }
}

// ---------------- launch ----------------
extern "C" void kernel_launch(void* const* d_in, const int* in_sizes, int n_in,
                              void* d_out, int out_size, void* d_ws, size_t ws_size,
                              hipStream_t stream) {
  (void)in_sizes; (void)n_in; (void)out_size;
  const float* Q    = (const float*)d_in[0];
  const float* C    = (const float*)d_in[1];
  const void*  mask = d_in[2];
  const float* W    = (const float*)d_in[3];
  const float* bias = (const float*)d_in[4];
  float* out_f = (float*)d_out;

  // ws layout (bytes): CB 134217728 | Qlo 67108864 | CT 67108864 | Wbf 4194304
  if (ws_size < 272629760ull) return;
  u16* CB  = (u16*)d_ws;
  u16* Qlo = (u16*)((char*)d_ws + 134217728);
  u16* CT  = (u16*)((char*)d_ws + 201326592);
  u16* Wbf = (u16*)((char*)d_ws + 268435456);

  // d_out[0:134M) holds Chi+Clo during K1, then Pbf after softmax, finally Out.
  u16* Chi = (u16*)d_out;
  u16* Clo = Chi + 33554432;
  u16* Pbf = (u16*)d_out;
  float* S = out_f + 33554432;   // attn region: raw scores -> probs in place

  conv_q<<<32768, 256, 0, stream>>>(Q, CB, Qlo);
  conv_c<<<dim3(16,32,16), 256, 0, stream>>>(C, Chi, Clo, CT);
  conv_w<<<2048, 256, 0, stream>>>(W, Wbf);

  k1_scores<<<4096, 256, 0, stream>>>(CB + 1024, Qlo, Chi, Clo, S);

  softmax_rows<<<32768, 256, 0, stream>>>(S, mask, Pbf);

  k3_mix<<<2048, 256, 0, stream>>>(Pbf, CT, CB);

  k4_out<<<2048, 256, 0, stream>>>(CB, Wbf, bias, out_f);
}